// Round 6
// baseline (110.922 us; speedup 1.0000x reference)
//
#include <hip/hip_runtime.h>
#include <math.h>

#define C_DIM 128
#define H_DIM 128
#define W_DIM 128
#define HW (H_DIM * W_DIM)
#define EPS_N 1e-12f

// ---------------- kernel 1: reciprocal clamped L2 norm of fused over C ----------------
// R1-proven structure: 2048 blocks x 256 thr, 8-way channel split + LDS reduce.
#define K1_PX 32
#define K1_NG 8
#define K1_CPG (C_DIM / K1_NG)
__global__ __launch_bounds__(256) void norms_fu(const float* __restrict__ fu,
                                                float* __restrict__ rn)
{
    __shared__ float part[K1_PX * 9];
    const int tid = threadIdx.x;
    const int px = tid & (K1_PX - 1);
    const int g = tid >> 5;
    const float* p = fu + (size_t)blockIdx.y * C_DIM * HW + (size_t)g * K1_CPG * HW
                     + blockIdx.x * K1_PX + px;
    float s = 0.f;
#pragma unroll
    for (int j = 0; j < K1_CPG; ++j) {
        const float v = p[(size_t)j * HW];
        s += v * v;
    }
    part[px * 9 + g] = s;
    __syncthreads();
    if (tid < K1_PX) {
        float t = 0.f;
#pragma unroll
        for (int gg = 0; gg < K1_NG; ++gg) t += part[tid * 9 + gg];
        rn[(size_t)blockIdx.y * HW + blockIdx.x * K1_PX + tid] =
            1.f / fmaxf(sqrtf(t), EPS_N);
    }
}

// ---------------- kernel 2: dots + softmax + aggregation ----------------
// Block = one image row, 512 thr (8 waves). Wave wv owns 16 channels.
// Lane: li = l&31 -> pixels [4li..4li+3] (float4); sub = l>>5 -> channel parity.
// One float4 wave-load covers a full 128-px row for 2 channels.
#define LD4(p) (*(const float4*)(p))
__global__ __launch_bounds__(512, 4) void asfr_main(const float* __restrict__ fe,
                                                    const float* __restrict__ fu,
                                                    const float* __restrict__ rn,
                                                    float* __restrict__ out)
{
    __shared__ float part[8][10][W_DIM];  // [wave][k(9 dots)+fe2][px] -> b128-writable
    __shared__ float wl[9][W_DIM];        // softmax weights, [k][px]
    __shared__ float n2r[3][W_DIM];       // staged reciprocal fu norms, 3 rows

    const int tid = threadIdx.x;
    const int l   = tid & 63;
    const int wv  = tid >> 6;
    const int li  = l & 31;
    const int sub = l >> 5;

    // XCD-chunked bijective swizzle (gridDim.x % 8 == 0): adjacent rows share an XCD L2.
    const int bid = blockIdx.x;
    const int cpx = gridDim.x >> 3;
    const int wb  = (bid & 7) * cpx + (bid >> 3);
    const int bz  = wb >> 7;
    const int row = wb & 127;

    const size_t imgbase = (size_t)bz * C_DIM * HW;
    const int c0  = wv * 16;
    const int px0 = 4 * li;

    // stage rn for rows row-1,row,row+1 (no dependence on pass 1)
    if (tid < 3 * W_DIM) {
        const int r = tid >> 7, c = tid & 127;
        const int nr = row + r - 1;
        float v = 1.f;
        if (nr >= 0 && nr < H_DIM) v = rn[(size_t)bz * HW + nr * W_DIM + c];
        n2r[r][c] = v;
    }

    const bool has_u = (row > 0), has_d = (row < H_DIM - 1);
    const int rup = has_u ? row - 1 : row;  // clamped; values masked to 0 below
    const int rdn = has_d ? row + 1 : row;

    const float* pfe = fe + imgbase + row * W_DIM + px0;
    const float* pfm = fu + imgbase + row * W_DIM + px0;
    const float* pfu = fu + imgbase + rup * W_DIM + px0;
    const float* pfd = fu + imgbase + rdn * W_DIM + px0;
    const float4 z4 = make_float4(0.f, 0.f, 0.f, 0.f);

    float4 dk[9];
#pragma unroll
    for (int k = 0; k < 9; ++k) dk[k] = z4;
    float4 fe24 = z4;

    // per-row dot accumulation: dk[r3+c].{x,y,z,w} = dot for px0..px0+3, kernel col c
    auto acc_row = [&](const float4 f, const float4 v, const int r3) {
        float lft = __shfl_up(v.w, 1);   lft = (li == 0)  ? 0.f : lft;
        float rgt = __shfl_down(v.x, 1); rgt = (li == 31) ? 0.f : rgt;
        dk[r3+0].x += f.x * lft;  dk[r3+1].x += f.x * v.x;  dk[r3+2].x += f.x * v.y;
        dk[r3+0].y += f.y * v.x;  dk[r3+1].y += f.y * v.y;  dk[r3+2].y += f.y * v.z;
        dk[r3+0].z += f.z * v.y;  dk[r3+1].z += f.z * v.z;  dk[r3+2].z += f.z * v.w;
        dk[r3+0].w += f.w * v.z;  dk[r3+1].w += f.w * v.w;  dk[r3+2].w += f.w * rgt;
    };

    // ---------------- pass 1: dots + ||fe||^2 (batched loads: 8 in flight) ----------------
#pragma unroll
    for (int b = 0; b < 4; ++b) {
        const size_t offA = (size_t)(c0 + 4 * b + sub) * HW;
        const size_t offB = offA + 2 * (size_t)HW;
        float4 fA = LD4(pfe + offA); float4 uA = LD4(pfu + offA);
        float4 mA = LD4(pfm + offA); float4 dA = LD4(pfd + offA);
        float4 fB = LD4(pfe + offB); float4 uB = LD4(pfu + offB);
        float4 mB = LD4(pfm + offB); float4 dB = LD4(pfd + offB);
        if (!has_u) { uA = z4; uB = z4; }
        if (!has_d) { dA = z4; dB = z4; }
        fe24.x += fA.x * fA.x + fB.x * fB.x;
        fe24.y += fA.y * fA.y + fB.y * fB.y;
        fe24.z += fA.z * fA.z + fB.z * fB.z;
        fe24.w += fA.w * fA.w + fB.w * fB.w;
        acc_row(fA, uA, 0); acc_row(fA, mA, 3); acc_row(fA, dA, 6);
        acc_row(fB, uB, 0); acc_row(fB, mB, 3); acc_row(fB, dB, 6);
    }

    // combine the two channel-parity halves (lane l <-> l+32 hold the same pixels)
#pragma unroll
    for (int k = 0; k < 9; ++k) {
        dk[k].x += __shfl_xor(dk[k].x, 32);
        dk[k].y += __shfl_xor(dk[k].y, 32);
        dk[k].z += __shfl_xor(dk[k].z, 32);
        dk[k].w += __shfl_xor(dk[k].w, 32);
    }
    fe24.x += __shfl_xor(fe24.x, 32);
    fe24.y += __shfl_xor(fe24.y, 32);
    fe24.z += __shfl_xor(fe24.z, 32);
    fe24.w += __shfl_xor(fe24.w, 32);

    if (sub == 0) {
#pragma unroll
        for (int k = 0; k < 9; ++k)
            *(float4*)&part[wv][k][px0] = dk[k];   // b128, conflict-free
        *(float4*)&part[wv][9][px0] = fe24;
    }
    __syncthreads();

    // ---------------- softmax (threads 0..127, one per pixel) ----------------
    if (tid < W_DIM) {
        const int px = tid;
        float dv[10];
#pragma unroll
        for (int k = 0; k < 10; ++k) {
            float s = 0.f;
#pragma unroll
            for (int sl = 0; sl < 8; ++sl) s += part[sl][k][px];
            dv[k] = s;
        }
        const float rfe = 1.f / fmaxf(sqrtf(dv[9]), EPS_N);
        float cs[9];
        float mx = -1e30f;
#pragma unroll
        for (int k = 0; k < 9; ++k) {
            const int di = k / 3, dj = k % 3;
            const int nr = row + di - 1;
            const int nc = px + dj - 1;
            const bool ok = (nr >= 0 && nr < H_DIM && nc >= 0 && nc < W_DIM);
            const int ncc = min(max(nc, 0), W_DIM - 1);
            const float cv = ok ? dv[k] * rfe * n2r[di][ncc] : 0.f;
            cs[k] = cv;
            mx = fmaxf(mx, cv);
        }
        float sum = 0.f;
#pragma unroll
        for (int k = 0; k < 9; ++k) { cs[k] = __expf(cs[k] - mx); sum += cs[k]; }
        const float is = 1.f / sum;
#pragma unroll
        for (int k = 0; k < 9; ++k) wl[k][px] = cs[k] * is;
    }
    __syncthreads();

    // ---------------- pass 2: weighted aggregation + residual ----------------
    float4 w4[9];
#pragma unroll
    for (int k = 0; k < 9; ++k) w4[k] = *(const float4*)&wl[k][px0];  // broadcast pair

    auto agg_row = [&](float4& acc, const float4 v, const int r3) {
        float lft = __shfl_up(v.w, 1);   lft = (li == 0)  ? 0.f : lft;
        float rgt = __shfl_down(v.x, 1); rgt = (li == 31) ? 0.f : rgt;
        acc.x += w4[r3+0].x * lft + w4[r3+1].x * v.x + w4[r3+2].x * v.y;
        acc.y += w4[r3+0].y * v.x + w4[r3+1].y * v.y + w4[r3+2].y * v.z;
        acc.z += w4[r3+0].z * v.y + w4[r3+1].z * v.z + w4[r3+2].z * v.w;
        acc.w += w4[r3+0].w * v.z + w4[r3+1].w * v.w + w4[r3+2].w * rgt;
    };

    float* pout = out + imgbase + row * W_DIM + px0;
#pragma unroll
    for (int b = 0; b < 4; ++b) {
        const size_t offA = (size_t)(c0 + 4 * b + sub) * HW;
        const size_t offB = offA + 2 * (size_t)HW;
        float4 fA = LD4(pfe + offA); float4 uA = LD4(pfu + offA);
        float4 mA = LD4(pfm + offA); float4 dA = LD4(pfd + offA);
        float4 fB = LD4(pfe + offB); float4 uB = LD4(pfu + offB);
        float4 mB = LD4(pfm + offB); float4 dB = LD4(pfd + offB);
        if (!has_u) { uA = z4; uB = z4; }
        if (!has_d) { dA = z4; dB = z4; }
        float4 accA = fA;  // residual
        float4 accB = fB;
        agg_row(accA, uA, 0); agg_row(accA, mA, 3); agg_row(accA, dA, 6);
        agg_row(accB, uB, 0); agg_row(accB, mB, 3); agg_row(accB, dB, 6);
        *(float4*)(pout + offA) = accA;
        *(float4*)(pout + offB) = accB;
    }
}

extern "C" void kernel_launch(void* const* d_in, const int* in_sizes, int n_in,
                              void* d_out, int out_size, void* d_ws, size_t ws_size,
                              hipStream_t stream) {
    const float* fe = (const float*)d_in[0];   // fe_lv
    const float* fu = (const float*)d_in[1];   // fused_features
    float* out = (float*)d_out;
    float* rn = (float*)d_ws;                  // B*HW floats
    const int B = in_sizes[0] / (C_DIM * HW);

    dim3 g1(HW / K1_PX, B);
    norms_fu<<<g1, 256, 0, stream>>>(fu, rn);

    dim3 g2(B * H_DIM);
    asfr_main<<<g2, 512, 0, stream>>>(fe, fu, rn, out);
}

// Round 7
// 50.553 us; speedup vs baseline: 2.1942x; 2.1942x over previous
//
#include <hip/hip_runtime.h>
#include <math.h>

#define C_DIM 128
#define H_DIM 128
#define W_DIM 128
#define HW (H_DIM * W_DIM)
#define EPS_N 1e-12f

// ---------------- kernel 1: reciprocal clamped L2 norm of fused over C ----------------
#define K1_PX 32
#define K1_NG 8
#define K1_CPG (C_DIM / K1_NG)
__global__ __launch_bounds__(256) void norms_fu(const float* __restrict__ fu,
                                                float* __restrict__ rn)
{
    __shared__ float part[K1_PX * 9];
    const int tid = threadIdx.x;
    const int px = tid & (K1_PX - 1);
    const int g = tid >> 5;
    const float* p = fu + (size_t)blockIdx.y * C_DIM * HW + (size_t)g * K1_CPG * HW
                     + blockIdx.x * K1_PX + px;
    float s = 0.f;
#pragma unroll
    for (int j = 0; j < K1_CPG; ++j) {
        const float v = p[(size_t)j * HW];
        s += v * v;
    }
    part[px * 9 + g] = s;
    __syncthreads();
    if (tid < K1_PX) {
        float t = 0.f;
#pragma unroll
        for (int gg = 0; gg < K1_NG; ++gg) t += part[tid * 9 + gg];
        rn[(size_t)blockIdx.y * HW + blockIdx.x * K1_PX + tid] =
            1.f / fmaxf(sqrtf(t), EPS_N);
    }
}

// ---------------- kernel 2: dots + softmax + aggregation ----------------
// Block = one image row, 512 thr (8 waves). Wave wv owns 16 channels.
// Lane: li = l&31 -> pixels [4li..4li+3] (float4); sub = l>>5 -> channel parity.
// NOTE: no min-wave clause — R3's (512,4) capped VGPR at 64 and spilled the
// float4 accumulators to scratch (WRITE_SIZE 193MB vs 33MB output).
#define LD4(p) (*(const float4*)(p))
__global__ __launch_bounds__(512) void asfr_main(const float* __restrict__ fe,
                                                 const float* __restrict__ fu,
                                                 const float* __restrict__ rn,
                                                 float* __restrict__ out)
{
    __shared__ float part[8][10][W_DIM];  // [wave][k(9 dots)+fe2][px]
    __shared__ float wl[9][W_DIM];        // softmax weights, [k][px]
    __shared__ float n2r[3][W_DIM];       // staged reciprocal fu norms, 3 rows

    const int tid = threadIdx.x;
    const int l   = tid & 63;
    const int wv  = tid >> 6;
    const int li  = l & 31;
    const int sub = l >> 5;

    // XCD-chunked bijective swizzle (gridDim.x % 8 == 0)
    const int bid = blockIdx.x;
    const int cpx = gridDim.x >> 3;
    const int wb  = (bid & 7) * cpx + (bid >> 3);
    const int bz  = wb >> 7;
    const int row = wb & 127;

    const size_t imgbase = (size_t)bz * C_DIM * HW;
    const int c0  = wv * 16;
    const int px0 = 4 * li;

    // stage rn for rows row-1,row,row+1
    if (tid < 3 * W_DIM) {
        const int r = tid >> 7, c = tid & 127;
        const int nr = row + r - 1;
        float v = 1.f;
        if (nr >= 0 && nr < H_DIM) v = rn[(size_t)bz * HW + nr * W_DIM + c];
        n2r[r][c] = v;
    }

    const bool has_u = (row > 0), has_d = (row < H_DIM - 1);
    const int rup = has_u ? row - 1 : row;
    const int rdn = has_d ? row + 1 : row;

    const float* pfe = fe + imgbase + row * W_DIM + px0;
    const float* pfm = fu + imgbase + row * W_DIM + px0;
    const float* pfu = fu + imgbase + rup * W_DIM + px0;
    const float* pfd = fu + imgbase + rdn * W_DIM + px0;
    const float4 z4 = make_float4(0.f, 0.f, 0.f, 0.f);

    float4 dk[9];
#pragma unroll
    for (int k = 0; k < 9; ++k) dk[k] = z4;
    float4 fe24 = z4;

    auto acc_row = [&](const float4 f, const float4 v, const int r3) {
        float lft = __shfl_up(v.w, 1);   lft = (li == 0)  ? 0.f : lft;
        float rgt = __shfl_down(v.x, 1); rgt = (li == 31) ? 0.f : rgt;
        dk[r3+0].x += f.x * lft;  dk[r3+1].x += f.x * v.x;  dk[r3+2].x += f.x * v.y;
        dk[r3+0].y += f.y * v.x;  dk[r3+1].y += f.y * v.y;  dk[r3+2].y += f.y * v.z;
        dk[r3+0].z += f.z * v.y;  dk[r3+1].z += f.z * v.z;  dk[r3+2].z += f.z * v.w;
        dk[r3+0].w += f.w * v.z;  dk[r3+1].w += f.w * v.w;  dk[r3+2].w += f.w * rgt;
    };

    // ---------------- pass 1: dots + ||fe||^2 ----------------
#pragma unroll
    for (int b = 0; b < 4; ++b) {
        const size_t offA = (size_t)(c0 + 4 * b + sub) * HW;
        const size_t offB = offA + 2 * (size_t)HW;
        float4 fA = LD4(pfe + offA); float4 uA = LD4(pfu + offA);
        float4 mA = LD4(pfm + offA); float4 dA = LD4(pfd + offA);
        float4 fB = LD4(pfe + offB); float4 uB = LD4(pfu + offB);
        float4 mB = LD4(pfm + offB); float4 dB = LD4(pfd + offB);
        if (!has_u) { uA = z4; uB = z4; }
        if (!has_d) { dA = z4; dB = z4; }
        fe24.x += fA.x * fA.x + fB.x * fB.x;
        fe24.y += fA.y * fA.y + fB.y * fB.y;
        fe24.z += fA.z * fA.z + fB.z * fB.z;
        fe24.w += fA.w * fA.w + fB.w * fB.w;
        acc_row(fA, uA, 0); acc_row(fA, mA, 3); acc_row(fA, dA, 6);
        acc_row(fB, uB, 0); acc_row(fB, mB, 3); acc_row(fB, dB, 6);
    }

    // combine the two channel-parity halves
#pragma unroll
    for (int k = 0; k < 9; ++k) {
        dk[k].x += __shfl_xor(dk[k].x, 32);
        dk[k].y += __shfl_xor(dk[k].y, 32);
        dk[k].z += __shfl_xor(dk[k].z, 32);
        dk[k].w += __shfl_xor(dk[k].w, 32);
    }
    fe24.x += __shfl_xor(fe24.x, 32);
    fe24.y += __shfl_xor(fe24.y, 32);
    fe24.z += __shfl_xor(fe24.z, 32);
    fe24.w += __shfl_xor(fe24.w, 32);

    if (sub == 0) {
#pragma unroll
        for (int k = 0; k < 9; ++k)
            *(float4*)&part[wv][k][px0] = dk[k];
        *(float4*)&part[wv][9][px0] = fe24;
    }
    __syncthreads();

    // ---------------- softmax (threads 0..127, one per pixel) ----------------
    if (tid < W_DIM) {
        const int px = tid;
        float dv[10];
#pragma unroll
        for (int k = 0; k < 10; ++k) {
            float s = 0.f;
#pragma unroll
            for (int sl = 0; sl < 8; ++sl) s += part[sl][k][px];
            dv[k] = s;
        }
        const float rfe = 1.f / fmaxf(sqrtf(dv[9]), EPS_N);
        float cs[9];
        float mx = -1e30f;
#pragma unroll
        for (int k = 0; k < 9; ++k) {
            const int di = k / 3, dj = k % 3;
            const int nr = row + di - 1;
            const int nc = px + dj - 1;
            const bool ok = (nr >= 0 && nr < H_DIM && nc >= 0 && nc < W_DIM);
            const int ncc = min(max(nc, 0), W_DIM - 1);
            const float cv = ok ? dv[k] * rfe * n2r[di][ncc] : 0.f;
            cs[k] = cv;
            mx = fmaxf(mx, cv);
        }
        float sum = 0.f;
#pragma unroll
        for (int k = 0; k < 9; ++k) { cs[k] = __expf(cs[k] - mx); sum += cs[k]; }
        const float is = 1.f / sum;
#pragma unroll
        for (int k = 0; k < 9; ++k) wl[k][px] = cs[k] * is;
    }
    __syncthreads();

    // ---------------- pass 2: weighted aggregation + residual ----------------
    float4 w4[9];
#pragma unroll
    for (int k = 0; k < 9; ++k) w4[k] = *(const float4*)&wl[k][px0];

    auto agg_row = [&](float4& acc, const float4 v, const int r3) {
        float lft = __shfl_up(v.w, 1);   lft = (li == 0)  ? 0.f : lft;
        float rgt = __shfl_down(v.x, 1); rgt = (li == 31) ? 0.f : rgt;
        acc.x += w4[r3+0].x * lft + w4[r3+1].x * v.x + w4[r3+2].x * v.y;
        acc.y += w4[r3+0].y * v.x + w4[r3+1].y * v.y + w4[r3+2].y * v.z;
        acc.z += w4[r3+0].z * v.y + w4[r3+1].z * v.z + w4[r3+2].z * v.w;
        acc.w += w4[r3+0].w * v.z + w4[r3+1].w * v.w + w4[r3+2].w * rgt;
    };

    float* pout = out + imgbase + row * W_DIM + px0;
#pragma unroll
    for (int b = 0; b < 4; ++b) {
        const size_t offA = (size_t)(c0 + 4 * b + sub) * HW;
        const size_t offB = offA + 2 * (size_t)HW;
        float4 fA = LD4(pfe + offA); float4 uA = LD4(pfu + offA);
        float4 mA = LD4(pfm + offA); float4 dA = LD4(pfd + offA);
        float4 fB = LD4(pfe + offB); float4 uB = LD4(pfu + offB);
        float4 mB = LD4(pfm + offB); float4 dB = LD4(pfd + offB);
        if (!has_u) { uA = z4; uB = z4; }
        if (!has_d) { dA = z4; dB = z4; }
        float4 accA = fA;
        float4 accB = fB;
        agg_row(accA, uA, 0); agg_row(accA, mA, 3); agg_row(accA, dA, 6);
        agg_row(accB, uB, 0); agg_row(accB, mB, 3); agg_row(accB, dB, 6);
        *(float4*)(pout + offA) = accA;
        *(float4*)(pout + offB) = accB;
    }
}

extern "C" void kernel_launch(void* const* d_in, const int* in_sizes, int n_in,
                              void* d_out, int out_size, void* d_ws, size_t ws_size,
                              hipStream_t stream) {
    const float* fe = (const float*)d_in[0];   // fe_lv
    const float* fu = (const float*)d_in[1];   // fused_features
    float* out = (float*)d_out;
    float* rn = (float*)d_ws;                  // B*HW floats
    const int B = in_sizes[0] / (C_DIM * HW);

    dim3 g1(HW / K1_PX, B);
    norms_fu<<<g1, 256, 0, stream>>>(fu, rn);

    dim3 g2(B * H_DIM);
    asfr_main<<<g2, 512, 0, stream>>>(fe, fu, rn, out);
}

// Round 11
// 38.262 us; speedup vs baseline: 2.8990x; 1.3212x over previous
//
#include <hip/hip_runtime.h>
#include <math.h>

#define C_DIM 128
#define H_DIM 128
#define W_DIM 128
#define HW (H_DIM * W_DIM)
#define EPS_N 1e-12f
#define NT 512
#define NW 8        // waves per block
#define CPW 16      // channels per wave
#define LD2(p) (*(const float2*)(p))

// ---------------- kernel 1: reciprocal clamped L2 norm of fused over C ----------------
// R1-measured-passing, verbatim.
#define K1_PX 32
#define K1_NG 8
#define K1_CPG (C_DIM / K1_NG)
__global__ __launch_bounds__(256) void norms_fu(const float* __restrict__ fu,
                                                float* __restrict__ rn)
{
    __shared__ float part[K1_PX * 9];
    const int tid = threadIdx.x;
    const int px = tid & (K1_PX - 1);
    const int g = tid >> 5;
    const float* p = fu + (size_t)blockIdx.y * C_DIM * HW + (size_t)g * K1_CPG * HW
                     + blockIdx.x * K1_PX + px;
    float s = 0.f;
#pragma unroll
    for (int j = 0; j < K1_CPG; ++j) {
        const float v = p[(size_t)j * HW];
        s += v * v;
    }
    part[px * 9 + g] = s;
    __syncthreads();
    if (tid < K1_PX) {
        float t = 0.f;
#pragma unroll
        for (int gg = 0; gg < K1_NG; ++gg) t += part[tid * 9 + gg];
        rn[(size_t)blockIdx.y * HW + blockIdx.x * K1_PX + tid] =
            1.f / fmaxf(sqrtf(t), EPS_N);
    }
}

// ---------------- kernel 2: dots + softmax + aggregation ----------------
// Composition of measured-passing pieces ONLY:
//  - R2's float2-lane shuffle compute (explicit edge masking), minus in-pass norms
//  - R4's rn->n2r staging and softmax (clamped ncc)
// Block = one image row, 8 waves; wave wv owns channels [16wv,16wv+16);
// lane l owns pixels 2l,2l+1. Channels batched 2 at a time (8 loads in flight).
__global__ __launch_bounds__(NT) void asfr_main2(const float* __restrict__ fe,
                                                 const float* __restrict__ fu,
                                                 const float* __restrict__ rn,
                                                 float* __restrict__ out)
{
    __shared__ float part[NW][10][W_DIM];  // 40 KB: [wave][9 dots + fe2][px]
    __shared__ float wl[9][W_DIM];         // 4.5 KB softmax weights
    __shared__ float n2r[3][W_DIM];        // 1.5 KB staged reciprocal fu norms

    const int tid = threadIdx.x;
    const int l   = tid & 63;
    const int wv  = tid >> 6;

    // XCD-chunked bijective swizzle (gridDim.x % 8 == 0)
    const int bid = blockIdx.x;
    const int cpx = gridDim.x >> 3;
    const int wb  = (bid & 7) * cpx + (bid >> 3);
    const int bz  = wb >> 7;
    const int row = wb & 127;

    const size_t imgbase = (size_t)bz * C_DIM * HW;
    const int c0   = wv * CPW;
    const int col0 = 2 * l;

    // stage n2r for rows row-1,row,row+1 (R4 verbatim; 384 < NT=512)
    if (tid < 3 * W_DIM) {
        const int r = tid >> 7, c = tid & 127;
        const int nr = row + r - 1;
        float v = 1.f;
        if (nr >= 0 && nr < H_DIM) v = rn[(size_t)bz * HW + nr * W_DIM + c];
        n2r[r][c] = v;
    }

    const bool has_u = (row > 0), has_d = (row < H_DIM - 1);
    const int rup = has_u ? row - 1 : row;   // clamped; loads zeroed below
    const int rdn = has_d ? row + 1 : row;

    const float* pfe = fe + imgbase + (size_t)c0 * HW + row * W_DIM + col0;
    const float* pfm = fu + imgbase + (size_t)c0 * HW + row * W_DIM + col0;
    const float* pfu = fu + imgbase + (size_t)c0 * HW + rup * W_DIM + col0;
    const float* pfd = fu + imgbase + (size_t)c0 * HW + rdn * W_DIM + col0;
    const float2 z2 = make_float2(0.f, 0.f);

    float2 dk[9];
#pragma unroll
    for (int k = 0; k < 9; ++k) dk[k] = z2;
    float2 fe2 = z2;

    // R2-measured-passing shuffle accumulate, explicit edge masking
    auto acc3 = [&](const float2 f, const float2 v, const int r3) {
        float lft = __shfl_up(v.y, 1);   lft = (l == 0)  ? 0.f : lft;   // col 2l-1
        float rgt = __shfl_down(v.x, 1); rgt = (l == 63) ? 0.f : rgt;   // col 2l+2
        dk[r3+0].x += f.x * lft;  dk[r3+1].x += f.x * v.x;  dk[r3+2].x += f.x * v.y;
        dk[r3+0].y += f.y * v.x;  dk[r3+1].y += f.y * v.y;  dk[r3+2].y += f.y * rgt;
    };

    // ---------------- pass 1: dots + ||fe||^2 (2 channels per batch) ----------------
#pragma unroll
    for (int jb = 0; jb < CPW / 2; ++jb) {
        const size_t offA = (size_t)(2 * jb) * HW;
        const size_t offB = offA + HW;
        float2 fA = LD2(pfe + offA); float2 uA = LD2(pfu + offA);
        float2 mA = LD2(pfm + offA); float2 dA = LD2(pfd + offA);
        float2 fB = LD2(pfe + offB); float2 uB = LD2(pfu + offB);
        float2 mB = LD2(pfm + offB); float2 dB = LD2(pfd + offB);
        if (!has_u) { uA = z2; uB = z2; }
        if (!has_d) { dA = z2; dB = z2; }
        fe2.x += fA.x * fA.x + fB.x * fB.x;
        fe2.y += fA.y * fA.y + fB.y * fB.y;
        acc3(fA, uA, 0); acc3(fA, mA, 3); acc3(fA, dA, 6);
        acc3(fB, uB, 0); acc3(fB, mB, 3); acc3(fB, dB, 6);
    }

    // per-wave partials (direct 8-slot layout)
#pragma unroll
    for (int k = 0; k < 9; ++k) *(float2*)&part[wv][k][col0] = dk[k];
    *(float2*)&part[wv][9][col0] = fe2;
    __syncthreads();

    // ---------------- softmax (threads 0..127, one per pixel; R4 verbatim) ----------------
    if (tid < W_DIM) {
        const int px = tid;
        float dv[10];
#pragma unroll
        for (int k = 0; k < 10; ++k) {
            float s = 0.f;
#pragma unroll
            for (int w = 0; w < NW; ++w) s += part[w][k][px];
            dv[k] = s;
        }
        const float rfe = 1.f / fmaxf(sqrtf(dv[9]), EPS_N);
        float cs[9];
        float mx = -1e30f;
#pragma unroll
        for (int k = 0; k < 9; ++k) {
            const int di = k / 3, dj = k % 3;
            const int nr = row + di - 1;
            const int nc = px + dj - 1;
            const bool ok = (nr >= 0 && nr < H_DIM && nc >= 0 && nc < W_DIM);
            const int ncc = min(max(nc, 0), W_DIM - 1);
            const float cv = ok ? dv[k] * rfe * n2r[di][ncc] : 0.f;
            cs[k] = cv;
            mx = fmaxf(mx, cv);
        }
        float sum = 0.f;
#pragma unroll
        for (int k = 0; k < 9; ++k) { cs[k] = __expf(cs[k] - mx); sum += cs[k]; }
        const float is = 1.f / sum;
#pragma unroll
        for (int k = 0; k < 9; ++k) wl[k][px] = cs[k] * is;
    }
    __syncthreads();

    // ---------------- pass 2: weighted aggregation + residual ----------------
    float2 w2[9];
#pragma unroll
    for (int k = 0; k < 9; ++k) w2[k] = *(const float2*)&wl[k][col0];

    auto agg3 = [&](float2& acc, const float2 v, const int r3) {
        float lft = __shfl_up(v.y, 1);   lft = (l == 0)  ? 0.f : lft;
        float rgt = __shfl_down(v.x, 1); rgt = (l == 63) ? 0.f : rgt;
        acc.x += w2[r3+0].x * lft  + w2[r3+1].x * v.x + w2[r3+2].x * v.y;
        acc.y += w2[r3+0].y * v.x  + w2[r3+1].y * v.y + w2[r3+2].y * rgt;
    };

    float* pout = out + imgbase + (size_t)c0 * HW + row * W_DIM + col0;
#pragma unroll
    for (int jb = 0; jb < CPW / 2; ++jb) {
        const size_t offA = (size_t)(2 * jb) * HW;
        const size_t offB = offA + HW;
        float2 fA = LD2(pfe + offA); float2 uA = LD2(pfu + offA);
        float2 mA = LD2(pfm + offA); float2 dA = LD2(pfd + offA);
        float2 fB = LD2(pfe + offB); float2 uB = LD2(pfu + offB);
        float2 mB = LD2(pfm + offB); float2 dB = LD2(pfd + offB);
        if (!has_u) { uA = z2; uB = z2; }
        if (!has_d) { dA = z2; dB = z2; }
        float2 accA = fA;   // residual
        float2 accB = fB;
        agg3(accA, uA, 0); agg3(accA, mA, 3); agg3(accA, dA, 6);
        agg3(accB, uB, 0); agg3(accB, mB, 3); agg3(accB, dB, 6);
        *(float2*)(pout + offA) = accA;
        *(float2*)(pout + offB) = accB;
    }
}

extern "C" void kernel_launch(void* const* d_in, const int* in_sizes, int n_in,
                              void* d_out, int out_size, void* d_ws, size_t ws_size,
                              hipStream_t stream) {
    const float* fe = (const float*)d_in[0];   // fe_lv
    const float* fu = (const float*)d_in[1];   // fused_features
    float* out = (float*)d_out;
    float* rn = (float*)d_ws;                  // B*HW floats
    const int B = in_sizes[0] / (C_DIM * HW);

    dim3 g1(HW / K1_PX, B);
    norms_fu<<<g1, 256, 0, stream>>>(fu, rn);

    dim3 g2(B * H_DIM);
    asfr_main2<<<g2, NT, 0, stream>>>(fe, fu, rn, out);
}